// Round 2
// baseline (7340.356 us; speedup 1.0000x reference)
//
#include <hip/hip_runtime.h>

#define Nn 50000
#define Ee 800000
#define Gg 64
#define KIN 133      // 2*64 + 4 + 1
#define ES 68        // padded LDS stride for lin1 tile (16B-aligned rows)
#define EPS 1e-5f

#define AS1 __attribute__((address_space(1)))
#define AS3 __attribute__((address_space(3)))

// async global->LDS, 16B per lane, wave-uniform LDS base
__device__ __forceinline__ void load_lds16(const float* g, float* s) {
    __builtin_amdgcn_global_load_lds((const AS1 void*)g, (AS3 void*)s, 16, 0, 0);
}

// stage `nfloats` contiguous floats global->LDS (nfloats % 1024 == 0)
__device__ __forceinline__ void stage_lin(const float* __restrict__ g0, float* l0,
                                          int t, int nfloats) {
    int l = t & 63, w = t >> 6;
    for (int ch = w; ch * 256 < nfloats; ch += 4)
        load_lds16(g0 + ch * 256 + l * 4, l0 + ch * 256);
}

// ---------------------------------------------------------------- small helpers

__global__ __launch_bounds__(256) void k_lin_in(const float* __restrict__ x,
    const float* __restrict__ W, const float* __restrict__ B, float* __restrict__ h)
{
    __shared__ float Ws[11 * 64];
    __shared__ float Bs[64];
    int t = threadIdx.x;
    for (int i = t; i < 11 * 64; i += 256) Ws[i] = W[i];
    if (t < 64) Bs[t] = B[t];
    __syncthreads();
    int i = blockIdx.x * 256 + t;
    if (i < Nn * 64) {
        int n = i >> 6, c = i & 63;
        float acc = Bs[c];
        #pragma unroll
        for (int k = 0; k < 11; k++) acc += x[n * 11 + k] * Ws[k * 64 + c];
        h[i] = acc;
    }
}

__global__ __launch_bounds__(256) void k_deg(const int* __restrict__ ei, float* __restrict__ deg)
{
    int e = blockIdx.x * 256 + threadIdx.x;
    if (e < Ee) atomicAdd(&deg[ei[Ee + e]], 1.f);
}

__global__ __launch_bounds__(256) void k_cnt(const int* __restrict__ batch, float* __restrict__ cnt)
{
    int n = blockIdx.x * 256 + threadIdx.x;
    if (n < Nn) atomicAdd(&cnt[batch[n]], 1.f);
}

// ------------------------------------------------- edge lin1 (133 -> 64) + stats
// Gather-staged with T14 register prefetch; output written TRANSPOSED to ybT[64][E].

__global__ __launch_bounds__(256) void k_edge_lin1(
    const float* __restrict__ h, const float* __restrict__ p,
    const float* __restrict__ ea, const int* __restrict__ ei,
    const float* __restrict__ W, const float* __restrict__ B,
    float* __restrict__ ybT, float* __restrict__ stats_out)
{
    __shared__ float Ws[KIN * 64];
    __shared__ float Bs[64];
    __shared__ float in_t[KIN * ES];
    int t = threadIdx.x;
    for (int i = t; i < KIN * 64; i += 256) Ws[i] = W[i];
    if (t < 64) Bs[t] = B[t];
    int tx = t & 15, ty = t >> 4;
    int cg = t & 15, es = t >> 4;       // staging: cols 4cg..+3, edges es*4..+3
    float ssum[4] = {0, 0, 0, 0}, ssq[4] = {0, 0, 0, 0};

    float4 hi[4], hj[4], eav;
    float rad = 0.f;
    int nt = Ee / 64;
    int tile = blockIdx.x;

    // ---- prefetch tile0 into regs
    {
        int te = tile * 64;
        #pragma unroll
        for (int i = 0; i < 4; i++) {
            int e = te + es * 4 + i;
            int sr = ei[e], ds = ei[Ee + e];
            hi[i] = *(const float4*)&h[(size_t)ds * 64 + 4 * cg];
            hj[i] = *(const float4*)&h[(size_t)sr * 64 + 4 * cg];
        }
        if (t < 64) {
            int e = te + t;
            int sr = ei[e], ds = ei[Ee + e];
            float dx = p[ds * 3 + 0] - p[sr * 3 + 0];
            float dy = p[ds * 3 + 1] - p[sr * 3 + 1];
            float dz = p[ds * 3 + 2] - p[sr * 3 + 2];
            rad = dx * dx + dy * dy + dz * dz;
            eav = *(const float4*)&ea[(size_t)e * 4];
        }
    }
    // ---- write tile0 into LDS (in-reg 4x4 transpose, b128 writes)
    {
        #pragma unroll
        for (int i = 0; i < 4; i++) {
            float4 v, u;
            v.x = ((const float*)&hi[0])[i]; v.y = ((const float*)&hi[1])[i];
            v.z = ((const float*)&hi[2])[i]; v.w = ((const float*)&hi[3])[i];
            u.x = ((const float*)&hj[0])[i]; u.y = ((const float*)&hj[1])[i];
            u.z = ((const float*)&hj[2])[i]; u.w = ((const float*)&hj[3])[i];
            *(float4*)&in_t[(4 * cg + i) * ES + es * 4] = v;
            *(float4*)&in_t[(64 + 4 * cg + i) * ES + es * 4] = u;
        }
        if (t < 64) {
            in_t[128 * ES + t] = rad;
            in_t[129 * ES + t] = eav.x; in_t[130 * ES + t] = eav.y;
            in_t[131 * ES + t] = eav.z; in_t[132 * ES + t] = eav.w;
        }
    }

    for (; tile < nt; tile += gridDim.x) {
        __syncthreads();                       // staged tile visible
        int nxt = tile + gridDim.x;
        if (nxt < nt) {                        // issue next tile's loads early
            int te = nxt * 64;
            #pragma unroll
            for (int i = 0; i < 4; i++) {
                int e = te + es * 4 + i;
                int sr = ei[e], ds = ei[Ee + e];
                hi[i] = *(const float4*)&h[(size_t)ds * 64 + 4 * cg];
                hj[i] = *(const float4*)&h[(size_t)sr * 64 + 4 * cg];
            }
            if (t < 64) {
                int e = te + t;
                int sr = ei[e], ds = ei[Ee + e];
                float dx = p[ds * 3 + 0] - p[sr * 3 + 0];
                float dy = p[ds * 3 + 1] - p[sr * 3 + 1];
                float dz = p[ds * 3 + 2] - p[sr * 3 + 2];
                rad = dx * dx + dy * dy + dz * dz;
                eav = *(const float4*)&ea[(size_t)e * 4];
            }
        }
        // ---- compute
        float acc[4][4];
        {
            float4 b4 = *(const float4*)&Bs[4 * ty];
            #pragma unroll
            for (int i = 0; i < 4; i++) {
                acc[i][0] = b4.x; acc[i][1] = b4.y; acc[i][2] = b4.z; acc[i][3] = b4.w;
            }
        }
        #pragma unroll 7
        for (int k = 0; k < KIN; k++) {
            float av[4], wv[4];
            *(float4*)av = *(const float4*)&in_t[k * ES + 4 * tx];
            *(float4*)wv = *(const float4*)&Ws[k * 64 + 4 * ty];
            #pragma unroll
            for (int i = 0; i < 4; i++)
                #pragma unroll
                for (int j = 0; j < 4; j++)
                    acc[i][j] += av[i] * wv[j];
        }
        int te = tile * 64;
        #pragma unroll
        for (int j = 0; j < 4; j++) {
            float4 o; o.x = acc[0][j]; o.y = acc[1][j]; o.z = acc[2][j]; o.w = acc[3][j];
            *(float4*)&ybT[(size_t)(4 * ty + j) * Ee + te + 4 * tx] = o;
            ssum[j] += o.x + o.y + o.z + o.w;
            ssq[j]  += o.x * o.x + o.y * o.y + o.z * o.z + o.w * o.w;
        }
        __syncthreads();                       // everyone done reading in_t
        if (nxt < nt) {                        // write prefetched regs -> LDS
            #pragma unroll
            for (int i = 0; i < 4; i++) {
                float4 v, u;
                v.x = ((const float*)&hi[0])[i]; v.y = ((const float*)&hi[1])[i];
                v.z = ((const float*)&hi[2])[i]; v.w = ((const float*)&hi[3])[i];
                u.x = ((const float*)&hj[0])[i]; u.y = ((const float*)&hj[1])[i];
                u.z = ((const float*)&hj[2])[i]; u.w = ((const float*)&hj[3])[i];
                *(float4*)&in_t[(4 * cg + i) * ES + es * 4] = v;
                *(float4*)&in_t[(64 + 4 * cg + i) * ES + es * 4] = u;
            }
            if (t < 64) {
                in_t[128 * ES + t] = rad;
                in_t[129 * ES + t] = eav.x; in_t[130 * ES + t] = eav.y;
                in_t[131 * ES + t] = eav.z; in_t[132 * ES + t] = eav.w;
            }
        }
    }
    #pragma unroll
    for (int j = 0; j < 4; j++) {
        float s = ssum[j], q = ssq[j];
        #pragma unroll
        for (int o2 = 1; o2 < 16; o2 <<= 1) { s += __shfl_xor(s, o2); q += __shfl_xor(q, o2); }
        if (tx == 0) {
            atomicAdd(&stats_out[4 * ty + j], s);
            atomicAdd(&stats_out[64 + 4 * ty + j], q);
        }
    }
}

// --------------------------- edge: bn+relu -> lin(64->64) [+m_aggr scatter] + stats
// ybT is channel-major [64][E]; tile staged via global_load_lds, double-buffered.

template<int AGGR>
__global__ __launch_bounds__(256) void k_edge_lin64(
    const float* __restrict__ stats_in, const float* __restrict__ gg,
    const float* __restrict__ be,
    const float* __restrict__ W, const float* __restrict__ B,
    const int* __restrict__ ei, float* __restrict__ magg,
    float* __restrict__ ybT, float* __restrict__ stats_out)
{
    __shared__ float Ws[64 * 64];
    __shared__ float in_t[2 * 64 * 64];
    __shared__ float ACs[128];
    __shared__ float Bs[64];
    int t = threadIdx.x;
    int l = t & 63, w = t >> 6;
    int lr = l >> 4, lc = (l & 15) * 4;

    stage_lin(W, Ws, t, 64 * 64);              // async weights
    if (t < 64) {
        float mean = stats_in[t] * (1.f / Ee);
        float var  = stats_in[64 + t] * (1.f / Ee) - mean * mean;
        float a = gg[t] * rsqrtf(var + EPS);
        ACs[2 * t] = a; ACs[2 * t + 1] = be[t] - mean * a; Bs[t] = B[t];
    }
    int nt = Ee / 64;
    int tile = blockIdx.x;
    {   // stage tile0 -> buf0
        int te = tile * 64;
        #pragma unroll
        for (int q = 0; q < 4; q++) {
            int ch = w * 4 + q;
            load_lds16(ybT + (size_t)(ch * 4 + lr) * Ee + te + lc, in_t + ch * 256);
        }
    }
    int tx = t & 15, ty = t >> 4;
    int cur = 0;
    float ssum[4] = {0, 0, 0, 0}, ssq[4] = {0, 0, 0, 0};

    for (; tile < nt; tile += gridDim.x) {
        __syncthreads();                       // drains vmcnt: buf[cur] ready
        int nxt = tile + gridDim.x;
        int dnode = 0;
        if (AGGR) dnode = ei[Ee + tile * 64 + l];
        if (nxt < nt) {                        // prefetch next tile -> buf[cur^1]
            int te = nxt * 64;
            float* dst = in_t + (cur ^ 1) * 4096;
            #pragma unroll
            for (int q = 0; q < 4; q++) {
                int ch = w * 4 + q;
                load_lds16(ybT + (size_t)(ch * 4 + lr) * Ee + te + lc, dst + ch * 256);
            }
        }
        const float* buf = in_t + cur * 4096;
        float acc[4][4];
        {
            float4 b4 = *(const float4*)&Bs[4 * ty];
            #pragma unroll
            for (int i = 0; i < 4; i++) {
                acc[i][0] = b4.x; acc[i][1] = b4.y; acc[i][2] = b4.z; acc[i][3] = b4.w;
            }
        }
        #pragma unroll 8
        for (int k = 0; k < 64; k++) {
            float av[4], wv[4];
            *(float4*)av = *(const float4*)&buf[k * 64 + 4 * tx];
            *(float4*)wv = *(const float4*)&Ws[k * 64 + 4 * ty];
            float a = ACs[2 * k], c = ACs[2 * k + 1];
            float r[4];
            #pragma unroll
            for (int i = 0; i < 4; i++) r[i] = fmaxf(av[i] * a + c, 0.f);
            #pragma unroll
            for (int i = 0; i < 4; i++)
                #pragma unroll
                for (int j = 0; j < 4; j++)
                    acc[i][j] += r[i] * wv[j];
        }
        if (AGGR) {                            // scatter normalized m into magg[dst]
            #pragma unroll
            for (int q = 0; q < 16; q++) {
                int k = w * 16 + q;
                float v = fmaxf(buf[k * 64 + l] * ACs[2 * k] + ACs[2 * k + 1], 0.f);
                atomicAdd(&magg[(size_t)dnode * 64 + k], v);
            }
        }
        int te = tile * 64;
        #pragma unroll
        for (int j = 0; j < 4; j++) {
            float4 o; o.x = acc[0][j]; o.y = acc[1][j]; o.z = acc[2][j]; o.w = acc[3][j];
            *(float4*)&ybT[(size_t)(4 * ty + j) * Ee + te + 4 * tx] = o;
            ssum[j] += o.x + o.y + o.z + o.w;
            ssq[j]  += o.x * o.x + o.y * o.y + o.z * o.z + o.w * o.w;
        }
        cur ^= 1;
    }
    #pragma unroll
    for (int j = 0; j < 4; j++) {
        float s = ssum[j], q = ssq[j];
        #pragma unroll
        for (int o2 = 1; o2 < 16; o2 <<= 1) { s += __shfl_xor(s, o2); q += __shfl_xor(q, o2); }
        if (tx == 0) {
            atomicAdd(&stats_out[4 * ty + j], s);
            atomicAdd(&stats_out[64 + 4 * ty + j], q);
        }
    }
}

// ------------------------------- edge: bn+relu -> pos_lin2 (64->1) -> scatter pos update

__global__ __launch_bounds__(256) void k_pos2(
    const float* __restrict__ stats_in, const float* __restrict__ gg, const float* __restrict__ be,
    const float* __restrict__ W2, const float* __restrict__ B2,
    const float* __restrict__ p, const int* __restrict__ ei,
    const float* __restrict__ ybT, float* __restrict__ pagg)
{
    __shared__ float As[64], Cs[64], Ws[64];
    int t = threadIdx.x;
    if (t < 64) {
        float mean = stats_in[t] * (1.f / Ee);
        float var  = stats_in[64 + t] * (1.f / Ee) - mean * mean;
        float a = gg[t] * rsqrtf(var + EPS);
        As[t] = a; Cs[t] = be[t] - mean * a; Ws[t] = W2[t];
    }
    __syncthreads();
    int e = blockIdx.x * 256 + t;
    float acc = B2[0];
    #pragma unroll 8
    for (int k = 0; k < 64; k++)
        acc += fmaxf(As[k] * ybT[(size_t)k * Ee + e] + Cs[k], 0.f) * Ws[k];
    int sr = ei[e], ds = ei[Ee + e];
    float dx = p[ds * 3 + 0] - p[sr * 3 + 0];
    float dy = p[ds * 3 + 1] - p[sr * 3 + 1];
    float dz = p[ds * 3 + 2] - p[sr * 3 + 2];
    atomicAdd(&pagg[ds * 3 + 0], dx * acc);
    atomicAdd(&pagg[ds * 3 + 1], dy * acc);
    atomicAdd(&pagg[ds * 3 + 2], dz * acc);
}

// ------------------------------------------- node: [h | m_aggr] (128 -> 64) + stats

__global__ __launch_bounds__(256) void k_node_lin1(
    const float* __restrict__ h, const float* __restrict__ magg,
    const float* __restrict__ W, const float* __restrict__ B,
    float* __restrict__ yn, float* __restrict__ stats_out)
{
    __shared__ float Ws[128 * 64];
    __shared__ float Bs[64];
    __shared__ float in_t[128 * ES];
    int t = threadIdx.x;
    for (int i = t; i < 128 * 64; i += 256) Ws[i] = W[i];
    if (t < 64) Bs[t] = B[t];
    int tx = t & 15, ty = t >> 4, c = t & 63, eg = t >> 6;
    float ssum[4] = {0, 0, 0, 0}, ssq[4] = {0, 0, 0, 0};
    int nT = (Nn + 63) / 64;
    for (int tile = blockIdx.x; tile < nT; tile += gridDim.x) {
        int te = tile * 64;
        __syncthreads();
        for (int e = eg; e < 64; e += 4) {
            int n = te + e;
            bool v = n < Nn;
            in_t[c * ES + e]        = v ? h[(size_t)n * 64 + c]    : 0.f;
            in_t[(64 + c) * ES + e] = v ? magg[(size_t)n * 64 + c] : 0.f;
        }
        __syncthreads();
        float acc[4][4];
        #pragma unroll
        for (int i = 0; i < 4; i++)
            #pragma unroll
            for (int j = 0; j < 4; j++) acc[i][j] = Bs[4 * ty + j];
        for (int k = 0; k < 128; k++) {
            float av[4], wv[4];
            *(float4*)av = *(const float4*)&in_t[k * ES + 4 * tx];
            *(float4*)wv = *(const float4*)&Ws[k * 64 + 4 * ty];
            #pragma unroll
            for (int i = 0; i < 4; i++)
                #pragma unroll
                for (int j = 0; j < 4; j++)
                    acc[i][j] += av[i] * wv[j];
        }
        #pragma unroll
        for (int i = 0; i < 4; i++) {
            int n = te + 4 * tx + i;
            if (n < Nn) {
                float4 o; o.x = acc[i][0]; o.y = acc[i][1]; o.z = acc[i][2]; o.w = acc[i][3];
                *(float4*)&yn[(size_t)n * 64 + 4 * ty] = o;
                #pragma unroll
                for (int j = 0; j < 4; j++) { ssum[j] += acc[i][j]; ssq[j] += acc[i][j] * acc[i][j]; }
            }
        }
    }
    #pragma unroll
    for (int j = 0; j < 4; j++) {
        float s = ssum[j], q = ssq[j];
        #pragma unroll
        for (int o2 = 1; o2 < 16; o2 <<= 1) { s += __shfl_xor(s, o2); q += __shfl_xor(q, o2); }
        if (tx == 0) {
            atomicAdd(&stats_out[4 * ty + j], s);
            atomicAdd(&stats_out[64 + 4 * ty + j], q);
        }
    }
}

// ------------------------------------------- node: bn+relu -> lin(64->64) + stats (in-place)

__global__ __launch_bounds__(256) void k_node_lin64(
    const float* __restrict__ stats_in, const float* __restrict__ gg, const float* __restrict__ be,
    const float* __restrict__ W, const float* __restrict__ B,
    float* __restrict__ yn, float* __restrict__ stats_out)
{
    __shared__ float Ws[64 * 64];
    __shared__ float As[64], Cs[64], Bs[64];
    __shared__ float in_t[64 * ES];
    int t = threadIdx.x;
    if (t < 64) {
        float mean = stats_in[t] * (1.f / Nn);
        float var  = stats_in[64 + t] * (1.f / Nn) - mean * mean;
        float a = gg[t] * rsqrtf(var + EPS);
        As[t] = a; Cs[t] = be[t] - mean * a; Bs[t] = B[t];
    }
    for (int i = t; i < 64 * 64; i += 256) Ws[i] = W[i];
    int tx = t & 15, ty = t >> 4, c = t & 63, eg = t >> 6;
    float ssum[4] = {0, 0, 0, 0}, ssq[4] = {0, 0, 0, 0};
    int nT = (Nn + 63) / 64;
    for (int tile = blockIdx.x; tile < nT; tile += gridDim.x) {
        int te = tile * 64;
        __syncthreads();
        for (int e = eg; e < 64; e += 4) {
            int n = te + e;
            float y = (n < Nn) ? yn[(size_t)n * 64 + c] : 0.f;
            in_t[c * ES + e] = fmaxf(As[c] * y + Cs[c], 0.f);
        }
        __syncthreads();
        float acc[4][4];
        #pragma unroll
        for (int i = 0; i < 4; i++)
            #pragma unroll
            for (int j = 0; j < 4; j++) acc[i][j] = Bs[4 * ty + j];
        for (int k = 0; k < 64; k++) {
            float av[4], wv[4];
            *(float4*)av = *(const float4*)&in_t[k * ES + 4 * tx];
            *(float4*)wv = *(const float4*)&Ws[k * 64 + 4 * ty];
            #pragma unroll
            for (int i = 0; i < 4; i++)
                #pragma unroll
                for (int j = 0; j < 4; j++)
                    acc[i][j] += av[i] * wv[j];
        }
        #pragma unroll
        for (int i = 0; i < 4; i++) {
            int n = te + 4 * tx + i;
            if (n < Nn) {
                float4 o; o.x = acc[i][0]; o.y = acc[i][1]; o.z = acc[i][2]; o.w = acc[i][3];
                *(float4*)&yn[(size_t)n * 64 + 4 * ty] = o;
                #pragma unroll
                for (int j = 0; j < 4; j++) { ssum[j] += acc[i][j]; ssq[j] += acc[i][j] * acc[i][j]; }
            }
        }
    }
    #pragma unroll
    for (int j = 0; j < 4; j++) {
        float s = ssum[j], q = ssq[j];
        #pragma unroll
        for (int o2 = 1; o2 < 16; o2 <<= 1) { s += __shfl_xor(s, o2); q += __shfl_xor(q, o2); }
        if (tx == 0) {
            atomicAdd(&stats_out[4 * ty + j], s);
            atomicAdd(&stats_out[64 + 4 * ty + j], q);
        }
    }
}

// ------------------------------------------- node: residual h += relu(bn(yn)); p update

__global__ __launch_bounds__(256) void k_node_update(
    const float* __restrict__ stats_in, const float* __restrict__ gg, const float* __restrict__ be,
    const float* __restrict__ yn, float* __restrict__ h,
    const float* __restrict__ p_in, float* __restrict__ p_out,
    const float* __restrict__ pagg, const float* __restrict__ deg)
{
    int i = blockIdx.x * 256 + threadIdx.x;
    if (i < Nn * 64) {
        int c = i & 63;
        float mean = stats_in[c] * (1.f / Nn);
        float var  = stats_in[64 + c] * (1.f / Nn) - mean * mean;
        float a = gg[c] * rsqrtf(var + EPS);
        float cc = be[c] - mean * a;
        h[i] += fmaxf(a * yn[i] + cc, 0.f);
    }
    if (i < Nn * 3) {
        float dg = fmaxf(deg[i / 3], 1.f);
        p_out[i] = p_in[i] + pagg[i] / dg;
    }
}

// ------------------------------------------- pooling + prediction head

__global__ __launch_bounds__(256) void k_pool(const int* __restrict__ batch,
    const float* __restrict__ h, float* __restrict__ pool)
{
    int i = blockIdx.x * 256 + threadIdx.x;
    if (i < Nn * 64) {
        int n = i >> 6, c = i & 63;
        atomicAdd(&pool[(size_t)batch[n] * 64 + c], h[i]);
    }
}

__global__ void k_out(const float* __restrict__ pool, const float* __restrict__ cnt,
    const float* __restrict__ W, const float* __restrict__ B, float* __restrict__ out)
{
    int g = threadIdx.x;
    if (g < 64) {
        float acc = 0.f;
        for (int c = 0; c < 64; c++) acc += pool[g * 64 + c] * W[c];
        out[g] = acc / fmaxf(cnt[g], 1.f) + B[0];
    }
}

// ---------------------------------------------------------------- launch

extern "C" void kernel_launch(void* const* d_in, const int* in_sizes, int n_in,
                              void* d_out, int out_size, void* d_ws, size_t ws_size,
                              hipStream_t stream)
{
    const float* x        = (const float*)d_in[0];
    const float* pos      = (const float*)d_in[1];
    const float* ea       = (const float*)d_in[2];
    const int*   ei       = (const int*)  d_in[3];
    const int*   batch    = (const int*)  d_in[4];
    const float* lin_in_w = (const float*)d_in[5];
    const float* lin_in_b = (const float*)d_in[6];
    const float* lin_pr_w = (const float*)d_in[7];
    const float* lin_pr_b = (const float*)d_in[8];
    const float* msg_w1   = (const float*)d_in[9];
    const float* msg_b1   = (const float*)d_in[10];
    const float* msg_g1   = (const float*)d_in[11];
    const float* msg_be1  = (const float*)d_in[12];
    const float* msg_w2   = (const float*)d_in[13];
    const float* msg_b2   = (const float*)d_in[14];
    const float* msg_g2   = (const float*)d_in[15];
    const float* msg_be2  = (const float*)d_in[16];
    const float* pos_w1   = (const float*)d_in[17];
    const float* pos_b1   = (const float*)d_in[18];
    const float* pos_g    = (const float*)d_in[19];
    const float* pos_be   = (const float*)d_in[20];
    const float* pos_w2   = (const float*)d_in[21];
    const float* pos_b2   = (const float*)d_in[22];
    const float* upd_w1   = (const float*)d_in[23];
    const float* upd_b1   = (const float*)d_in[24];
    const float* upd_g1   = (const float*)d_in[25];
    const float* upd_be1  = (const float*)d_in[26];
    const float* upd_w2   = (const float*)d_in[27];
    const float* upd_b2   = (const float*)d_in[28];
    const float* upd_g2   = (const float*)d_in[29];
    const float* upd_be2  = (const float*)d_in[30];
    float* out = (float*)d_out;

    float* ws = (float*)d_ws;
    size_t o = 0;
    float* h    = ws + o; o += (size_t)Nn * 64;
    float* ybT  = ws + o; o += (size_t)Ee * 64;   // channel-major [64][E]
    float* yn   = ws + o; o += (size_t)Nn * 64;
    float* magg = ws + o; o += (size_t)Nn * 64;   // magg + pagg contiguous (one memset)
    float* pagg = ws + o; o += (size_t)Nn * 3;
    float* pws  = ws + o; o += (size_t)Nn * 3;
    float* stats= ws + o; o += 1280;              // stats..deg contiguous (one memset)
    float* pool = ws + o; o += 64 * 64;
    float* cnt  = ws + o; o += 64;
    float* deg  = ws + o; o += Nn;
    if (ws_size < o * sizeof(float)) return;

    hipMemsetAsync(stats, 0, (size_t)(1280 + 64 * 64 + 64 + Nn) * sizeof(float), stream);
    k_lin_in<<<(Nn * 64 + 255) / 256, 256, 0, stream>>>(x, lin_in_w, lin_in_b, h);
    k_deg<<<(Ee + 255) / 256, 256, 0, stream>>>(ei, deg);
    k_cnt<<<(Nn + 255) / 256, 256, 0, stream>>>(batch, cnt);

    for (int l = 0; l < 2; l++) {
        hipMemsetAsync(magg, 0, ((size_t)Nn * 64 + (size_t)Nn * 3) * sizeof(float), stream);
        const float* pc = (l == 0) ? pos : pws;
        float* st = stats + (size_t)l * 5 * 128;
        k_edge_lin1<<<512, 256, 0, stream>>>(h, pc, ea, ei,
            msg_w1 + (size_t)l * KIN * 64, msg_b1 + l * 64, ybT, st + 0 * 128);
        k_edge_lin64<0><<<768, 256, 0, stream>>>(st + 0 * 128, msg_g1 + l * 64, msg_be1 + l * 64,
            msg_w2 + (size_t)l * 64 * 64, msg_b2 + l * 64, ei, nullptr, ybT, st + 1 * 128);
        k_edge_lin64<1><<<768, 256, 0, stream>>>(st + 1 * 128, msg_g2 + l * 64, msg_be2 + l * 64,
            pos_w1 + (size_t)l * 64 * 64, pos_b1 + l * 64, ei, magg, ybT, st + 2 * 128);
        k_pos2<<<Ee / 256, 256, 0, stream>>>(st + 2 * 128, pos_g + l * 64, pos_be + l * 64,
            pos_w2 + l * 64, pos_b2 + l, pc, ei, ybT, pagg);
        k_node_lin1<<<782, 256, 0, stream>>>(h, magg,
            upd_w1 + (size_t)l * 128 * 64, upd_b1 + l * 64, yn, st + 3 * 128);
        k_node_lin64<<<782, 256, 0, stream>>>(st + 3 * 128, upd_g1 + l * 64, upd_be1 + l * 64,
            upd_w2 + (size_t)l * 64 * 64, upd_b2 + l * 64, yn, st + 4 * 128);
        k_node_update<<<(Nn * 64 + 255) / 256, 256, 0, stream>>>(st + 4 * 128,
            upd_g2 + l * 64, upd_be2 + l * 64, yn, h, pc, pws, pagg, deg);
    }
    k_pool<<<(Nn * 64 + 255) / 256, 256, 0, stream>>>(batch, h, pool);
    k_out<<<1, 64, 0, stream>>>(pool, cnt, lin_pr_w, lin_pr_b, out);
}